// Round 12
// baseline (249.093 us; speedup 1.0000x reference)
//
#include <hip/hip_runtime.h>
#include <math.h>

typedef unsigned short u16;
typedef unsigned int u32;
typedef __attribute__((ext_vector_type(8))) __bf16 bf16x8;
typedef __attribute__((ext_vector_type(4))) float f32x4;
typedef __attribute__((ext_vector_type(8))) unsigned short u16x8;

__device__ __forceinline__ u16 f2bf(float f) {
    u32 u = __builtin_bit_cast(u32, f);
    u32 r = (u + 0x7fffu + ((u >> 16) & 1u)) >> 16;
    return (u16)r;
}
__device__ __forceinline__ float bf2f(u16 h) {
    return __builtin_bit_cast(float, (u32)h << 16);
}
__device__ __forceinline__ float exp2v(float x) {
    float r;
    asm("v_exp_f32 %0, %1" : "=v"(r) : "v"(x));
    return r;
}
__device__ __forceinline__ u32 cvtpk(float lo, float hi) {
    u32 r;
    asm("v_cvt_pk_bf16_f32 %0, %1, %2" : "=v"(r) : "v"(lo), "v"(hi));
    return r;
}

#define GL16(gp, lp) __builtin_amdgcn_global_load_lds( \
    (const __attribute__((address_space(1))) u32*)(gp), \
    (__attribute__((address_space(3))) u32*)(lp), 16, 0, 0)

// RoPE a bf16x8 fragment: 4 (even,odd) pairs, cs4 = 4 (cos,sin) entries
__device__ __forceinline__ bf16x8 ropeQK(bf16x8 v, const float2* __restrict__ cs4) {
    union { bf16x8 b; u32 w[4]; } in, out;
    in.b = v;
#pragma unroll
    for (int i = 0; i < 4; ++i) {
        float2 cs = cs4[i];
        float e = bf2f((u16)(in.w[i] & 0xffff));
        float o = bf2f((u16)(in.w[i] >> 16));
        out.w[i] = cvtpk(e * cs.x - o * cs.y, fmaf(e, cs.y, o * cs.x));
    }
    return out.b;
}

// ---------------------------------------------------------------------------
// prep: merged f2bker (blocks 0..4095) + wtrans Wqkv (4096..4863) +
// wtrans Wproj (4864..5119) + rope_tab (5120..5375). Bodies unchanged.
__global__ __launch_bounds__(256) void prep(
    const float* __restrict__ x, u16* __restrict__ xb,
    const float* __restrict__ Wqkv, u16* __restrict__ WqkvT,
    const float* __restrict__ Wproj, u16* __restrict__ WprojT,
    float2* __restrict__ tab) {
    __shared__ u16 t[64 * 65];
    const int bid = (int)blockIdx.x;
    const int tid = threadIdx.x;

    if (bid < 4096) {
        size_t i = ((size_t)bid * 256 + tid) * 8;
        float4 a = *(const float4*)(x + i);
        float4 b = *(const float4*)(x + i + 4);
        u16x8 w;
        w[0] = f2bf(a.x); w[1] = f2bf(a.y); w[2] = f2bf(a.z); w[3] = f2bf(a.w);
        w[4] = f2bf(b.x); w[5] = f2bf(b.y); w[6] = f2bf(b.z); w[7] = f2bf(b.w);
        *(u16x8*)(xb + i) = w;
        return;
    }
    if (bid < 5120) {
        const float* in; u16* out; int R = 1024, C; int c0, r0;
        if (bid < 4864) {
            in = Wqkv; out = WqkvT; C = 3072;
            int idx = bid - 4096;
            c0 = (idx % 48) * 64; r0 = (idx / 48) * 64;
        } else {
            in = Wproj; out = WprojT; C = 1024;
            int idx = bid - 4864;
            c0 = (idx % 16) * 64; r0 = (idx / 16) * 64;
        }
#pragma unroll
        for (int it = 0; it < 4; ++it) {
            int f = it * 256 + tid;
            int row = f >> 4, c4 = (f & 15) * 4;
            float4 v = *(const float4*)(in + (size_t)(r0 + row) * C + c0 + c4);
            t[row * 65 + c4 + 0] = f2bf(v.x);
            t[row * 65 + c4 + 1] = f2bf(v.y);
            t[row * 65 + c4 + 2] = f2bf(v.z);
            t[row * 65 + c4 + 3] = f2bf(v.w);
        }
        __syncthreads();
#pragma unroll
        for (int it = 0; it < 2; ++it) {
            int f = it * 256 + tid;
            int oc = f >> 3, r8 = (f & 7) * 8;
            u16x8 w;
#pragma unroll
            for (int j = 0; j < 8; ++j) w[j] = t[(r8 + j) * 65 + oc];
            *(u16x8*)(out + (size_t)(c0 + oc) * R + r0 + r8) = w;
        }
        return;
    }
    {
        int i = (bid - 5120) * 256 + tid;   // 65536
        int tpos = i >> 5, d2 = i & 31;
        float invf = powf(10000.f, -(float)(2 * d2) / 64.f);
        float fr = (float)tpos * invf;
        tab[i] = make_float2(cosf(fr), sinf(fr));
    }
}

// RoPE in-place on K only (B,H,T,D) bf16 (Q is roped inside attn)
__global__ __launch_bounds__(256) void rope_ip(u16* __restrict__ K,
                                               const float2* __restrict__ tab) {
    int i = blockIdx.x * 256 + threadIdx.x;   // 4,194,304 pairs
    u32* p = (u32*)K + i;
    int d2 = i & 31, tpos = (i >> 5) & 2047;
    float2 cs = tab[tpos * 32 + d2];
    u32 v = *p;
    float xe = bf2f((u16)(v & 0xffff));
    float xo = bf2f((u16)(v >> 16));
    float re = xe * cs.x - xo * cs.y;
    float ro = xe * cs.y + xo * cs.x;
    *p = (u32)f2bf(re) | ((u32)f2bf(ro) << 16);
}

// ---------------------------------------------------------------------------
// QKV GEMM: 128x192 tile, BK=64, 384 threads = 6 waves (2x3 of 64x64 —
// per-wave geometry unchanged from the verified r9 body). Depth-2 counted
// vmcnt: each wave issues EXACTLY 7 global_load_lds per K-tile (42 units,
// 2 benign duplicates), so vmcnt(7) waits tile t only. 80 KB LDS x 2
// blocks/CU = 160 KB. Grid 1024 = 2 exact rounds. Same swizzle involution.
// Scatter epilogue with per-element part decode (tiles cross Q/K/V bounds).
__global__ __launch_bounds__(384, 3) void gemm_qkv(
    const u16* __restrict__ A, const u16* __restrict__ Bt,
    const float* __restrict__ bias,
    u16* __restrict__ Qb, u16* __restrict__ Kb, u16* __restrict__ VbT) {
    extern __shared__ char lsb[];              // [2][80KB/2]: A 16KB + B 24KB
    const int tid = threadIdx.x;
    const int w = tid >> 6, lane = tid & 63;
    const int c = lane & 15, g = lane >> 4;
    const int wr = w / 3, wc = w % 3;          // 2 x 3 wave grid

    // 2D-clustered XCD mapping: 1024 = 8 xcd * 8 cluster * 16 in-cluster
    const int bid = (int)blockIdx.x;
    const int xcd = bid & 7, s = bid >> 3;
    const int cidx = s >> 4, w2 = s & 15;      // nbx=16 -> ncc=4
    const int by = xcd * 8 + (cidx >> 2) * 4 + (w2 >> 2);
    const int bx = (cidx & 3) * 4 + (w2 & 3);
    const int m0 = by * 128, n0 = bx * 192;

    f32x4 acc[4][4] = {};

    // staging: 42 units of 1KB (8 rows x 64 cols bf16); unit u -> wave u%6.
    // lane covers row u*8 + (lane>>3), swizzled col.
    const int r8 = lane >> 3;                  // 0..7
    const unsigned cbL = ((unsigned)(lane & 7) * 16) ^ ((unsigned)r8 << 4);
    const u16* gA0 = A + (size_t)(m0 + r8) * 1024 + (cbL >> 1);
    const u16* gB0 = Bt + (size_t)(n0 + r8) * 1024 + (cbL >> 1);

#define STG(t_, buf_) do {                                                    \
        char* _b = lsb + (buf_) * 40960;                                      \
        for (int u = w; u < 42; u += 6) {                                     \
            int uu = (u < 40) ? u : u - 40;                                   \
            const u16* _g = (uu < 16 ? gA0 + (size_t)uu * 8192                \
                                     : gB0 + (size_t)(uu - 16) * 8192) + (t_) * 64; \
            char* _l = _b + (uu < 16 ? uu * 1024 : 16384 + (uu - 16) * 1024); \
            GL16(_g, _l);                                                     \
        }                                                                     \
    } while (0)

    const unsigned swz = ((unsigned)(c & 7)) << 4;

    STG(0, 0);
    STG(1, 1);

    for (int t = 0; t < 16; ++t) {
        const int buf = t & 1;
        __builtin_amdgcn_sched_barrier(0);
        if (t == 15) asm volatile("s_waitcnt vmcnt(0)" ::: "memory");
        else         asm volatile("s_waitcnt vmcnt(7)" ::: "memory");
        __builtin_amdgcn_sched_barrier(0);
        __builtin_amdgcn_s_barrier();           // buf[t&1] fully staged
        __builtin_amdgcn_sched_barrier(0);

        const char* la = lsb + buf * 40960;
        const char* lb2 = la + 16384;
        bf16x8 af[4][2], bfr[4][2];
#pragma unroll
        for (int i = 0; i < 4; ++i) {
            unsigned rb = (unsigned)((wr * 64 + i * 16 + c) * 128);
            af[i][0] = *(const bf16x8*)(la + ((rb + g * 16) ^ swz));
            af[i][1] = *(const bf16x8*)(la + ((rb + 64 + g * 16) ^ swz));
        }
#pragma unroll
        for (int j = 0; j < 4; ++j) {
            unsigned rb = (unsigned)((wc * 64 + j * 16 + c) * 128);
            bfr[j][0] = *(const bf16x8*)(lb2 + ((rb + g * 16) ^ swz));
            bfr[j][1] = *(const bf16x8*)(lb2 + ((rb + 64 + g * 16) ^ swz));
        }
        __builtin_amdgcn_s_setprio(1);
#pragma unroll
        for (int i = 0; i < 4; ++i)
#pragma unroll
            for (int j = 0; j < 4; ++j) {
                acc[i][j] = __builtin_amdgcn_mfma_f32_16x16x32_bf16(af[i][0], bfr[j][0], acc[i][j], 0, 0, 0);
                acc[i][j] = __builtin_amdgcn_mfma_f32_16x16x32_bf16(af[i][1], bfr[j][1], acc[i][j], 0, 0, 0);
            }
        __builtin_amdgcn_s_setprio(0);
        __builtin_amdgcn_sched_barrier(0);
        asm volatile("s_waitcnt lgkmcnt(0)" ::: "memory");
        __builtin_amdgcn_s_barrier();           // all reads of buf done
        __builtin_amdgcn_sched_barrier(0);
        if (t < 14) STG(t + 2, buf);            // overwrite buf for t+2
    }
#undef STG

#pragma unroll
    for (int i = 0; i < 4; ++i)
#pragma unroll
        for (int r = 0; r < 4; ++r) {
            int m = m0 + wr * 64 + i * 16 + g * 4 + r;
            int b = m >> 11, tt = m & 2047;
#pragma unroll
            for (int j = 0; j < 4; ++j) {
                int n = n0 + wc * 64 + j * 16 + c;
                int part = n >> 10;
                int e = n & 1023, hh = e >> 6, d = e & 63;
                float v = acc[i][j][r] + bias[n];
                u16 bv = f2bf(v);
                if (part == 0)
                    Qb[(((size_t)b * 16 + hh) * 2048 + tt) * 64 + d] = bv;
                else if (part == 1)
                    Kb[(((size_t)b * 16 + hh) * 2048 + tt) * 64 + d] = bv;
                else
                    VbT[(((size_t)b * 16 + hh) * 64 + d) * 2048 + tt] = bv;
            }
        }
}

// ---------------------------------------------------------------------------
// Proj GEMM: r11 body unchanged (depth-2 counted vmcnt, BK=64, 128x128,
// clustered XCD map). Cf[m][n] = acc + bias[n], fp32.
__global__ __launch_bounds__(256, 2) void gemm_proj(
    const u16* __restrict__ A, const u16* __restrict__ Bt,
    const float* __restrict__ bias, float* __restrict__ Cf,
    int N, int nbx) {
    __shared__ __align__(16) u16 ls[2][2][128 * 64];
    const int tid = threadIdx.x;
    const int w = tid >> 6, lane = tid & 63;
    const int c = lane & 15, g = lane >> 4;
    const int wr = w >> 1, wc = w & 1;

    const int bid = (int)blockIdx.x;
    const int xcd = bid & 7, s = bid >> 3;
    const int ncc = nbx >> 2;
    const int cidx = s >> 4, w2 = s & 15;
    const int by = xcd * 8 + (cidx / ncc) * 4 + (w2 >> 2);
    const int bx = (cidx % ncc) * 4 + (w2 & 3);
    const int m0 = by * 128, n0 = bx * 128;

    f32x4 acc[4][4] = {};

    const int rl = tid >> 3;
    const unsigned cb = ((unsigned)(tid & 7) * 16) ^ (((unsigned)rl & 7) << 4);
    const u16* gA = A + (size_t)(m0 + rl) * 1024 + (cb >> 1);
    const u16* gB = Bt + (size_t)(n0 + rl) * 1024 + (cb >> 1);
    const unsigned wb = (unsigned)__builtin_amdgcn_readfirstlane(w * 1024);
    char* lsb = (char*)ls;

#define STAGE(t_, buf_) do {                                                  \
        const u16* _ga = gA + (t_) * 64;                                      \
        const u16* _gb = gB + (t_) * 64;                                      \
        char* _la = lsb + (buf_) * 32768 + wb;                                \
        char* _lb = _la + 16384;                                              \
        GL16(_ga, _la);                                                       \
        GL16(_ga + 32 * 1024, _la + 4096);                                    \
        GL16(_ga + 64 * 1024, _la + 8192);                                    \
        GL16(_ga + 96 * 1024, _la + 12288);                                   \
        GL16(_gb, _lb);                                                       \
        GL16(_gb + 32 * 1024, _lb + 4096);                                    \
        GL16(_gb + 64 * 1024, _lb + 8192);                                    \
        GL16(_gb + 96 * 1024, _lb + 12288);                                   \
    } while (0)

    const unsigned swz = ((unsigned)(c & 7)) << 4;

    STAGE(0, 0);
    STAGE(1, 1);

    for (int t = 0; t < 16; ++t) {
        const int buf = t & 1;
        __builtin_amdgcn_sched_barrier(0);
        if (t == 15) asm volatile("s_waitcnt vmcnt(0)" ::: "memory");
        else         asm volatile("s_waitcnt vmcnt(8)" ::: "memory");
        __builtin_amdgcn_sched_barrier(0);
        __builtin_amdgcn_s_barrier();
        __builtin_amdgcn_sched_barrier(0);

        const char* la = lsb + buf * 32768;
        const char* lb2 = la + 16384;
        bf16x8 af[4][2], bfr[4][2];
#pragma unroll
        for (int i = 0; i < 4; ++i) {
            unsigned rb = (unsigned)((wr * 64 + i * 16 + c) * 128);
            af[i][0] = *(const bf16x8*)(la + ((rb + g * 16) ^ swz));
            af[i][1] = *(const bf16x8*)(la + ((rb + 64 + g * 16) ^ swz));
        }
#pragma unroll
        for (int j = 0; j < 4; ++j) {
            unsigned rb = (unsigned)((wc * 64 + j * 16 + c) * 128);
            bfr[j][0] = *(const bf16x8*)(lb2 + ((rb + g * 16) ^ swz));
            bfr[j][1] = *(const bf16x8*)(lb2 + ((rb + 64 + g * 16) ^ swz));
        }
        __builtin_amdgcn_s_setprio(1);
#pragma unroll
        for (int i = 0; i < 4; ++i)
#pragma unroll
            for (int j = 0; j < 4; ++j) {
                acc[i][j] = __builtin_amdgcn_mfma_f32_16x16x32_bf16(af[i][0], bfr[j][0], acc[i][j], 0, 0, 0);
                acc[i][j] = __builtin_amdgcn_mfma_f32_16x16x32_bf16(af[i][1], bfr[j][1], acc[i][j], 0, 0, 0);
            }
        __builtin_amdgcn_s_setprio(0);
        __builtin_amdgcn_sched_barrier(0);
        asm volatile("s_waitcnt lgkmcnt(0)" ::: "memory");
        __builtin_amdgcn_s_barrier();
        __builtin_amdgcn_sched_barrier(0);
        if (t < 14) STAGE(t + 2, buf);
    }
#undef STAGE

#pragma unroll
    for (int i = 0; i < 4; ++i)
#pragma unroll
        for (int r = 0; r < 4; ++r) {
            int m = m0 + wr * 64 + i * 16 + g * 4 + r;
#pragma unroll
            for (int j = 0; j < 4; ++j) {
                int n = n0 + wc * 64 + j * 16 + c;
                Cf[(size_t)m * N + n] = acc[i][j][r] + bias[n];
            }
        }
}

// ---------------------------------------------------------------------------
// Flash attention, swapped-operand form; Q roped in-register at start.
// 1024 blocks, 256 threads (4 waves x 32 q each; block = 128 q rows).
__global__ __launch_bounds__(256, 3) void attn_fwd(
    const u16* __restrict__ Qb, const u16* __restrict__ Kb,
    const u16* __restrict__ VbT, u16* __restrict__ Ob,
    const float2* __restrict__ tab) {
    __shared__ __align__(16) u16 Kt[2][4096];   // [buf][kv=64][d=64] swizzled
    __shared__ __align__(16) u16 Vt[2][4096];   // [buf][d=64][kv=64] swizzled
    __shared__ __align__(16) u16 Pt[4][2048];   // per-wave [q=32][kv=64] swizzled
    const int tid = threadIdx.x, wv = tid >> 6, lane = tid & 63;
    const int g = lane >> 4, c = lane & 15;
    const int bid = blockIdx.x;                 // 0..1023
    const int xcd = bid & 7, slot = bid >> 3;
    const int bh = (xcd << 3) | (slot >> 4);
    const int blk = 15 - (slot & 15);
    const int b = bh >> 4, h = bh & 15;
    const int q0 = blk * 128;
    const int q0w = q0 + wv * 32;
    const int qlo = q0w + c, qhi = q0w + 16 + c;
    const float CSC = 0.18033688011112042f;     // 0.125 * log2(e)

    const u16* qp = Qb + ((size_t)bh * 2048 + qlo) * 64 + g * 8;
    const float2* tql = tab + qlo * 32 + g * 4;
    const float2* tqh = tab + qhi * 32 + g * 4;
    bf16x8 bq0l = ropeQK(*(const bf16x8*)(qp), tql);
    bf16x8 bq1l = ropeQK(*(const bf16x8*)(qp + 32), tql + 16);
    bf16x8 bq0h = ropeQK(*(const bf16x8*)(qp + 16 * 64), tqh);
    bf16x8 bq1h = ropeQK(*(const bf16x8*)(qp + 16 * 64 + 32), tqh + 16);

    float m_lo = -INFINITY, l_lo = 0.f;
    float m_hi = -INFINITY, l_hi = 0.f;
    f32x4 accL[4] = {}, accH[4] = {};

    const int stRow = tid >> 3;                 // 0..31
    const int stCol = (tid & 7) * 8;            // 0..56
    const u16* gK = Kb + (size_t)bh * 2048 * 64 + (size_t)stRow * 64 + stCol;
    const u16* gV = VbT + (size_t)bh * 64 * 2048 + (size_t)stRow * 2048 + stCol;
    const unsigned sw8 = (unsigned)(stRow & 7) << 4;
    const unsigned sAd0 = ((unsigned)(stRow * 128 + stCol * 2)) ^ sw8;
    const unsigned sAd1 = ((unsigned)((stRow + 32) * 128 + stCol * 2)) ^ sw8;
    const unsigned swz = (unsigned)(c & 7) << 4;
    char* pw = (char*)&Pt[wv][0];

    const int ktend = 2 * blk + 1;
    const int ktmax_w = (q0w + 31) >> 6;

    u16x8 kr0 = *(const u16x8*)(gK);
    u16x8 kr1 = *(const u16x8*)(gK + 32 * 64);
    u16x8 vr0 = *(const u16x8*)(gV);
    u16x8 vr1 = *(const u16x8*)(gV + 32 * 2048);
    *(u16x8*)((char*)Kt[0] + sAd0) = kr0;
    *(u16x8*)((char*)Kt[0] + sAd1) = kr1;
    *(u16x8*)((char*)Vt[0] + sAd0) = vr0;
    *(u16x8*)((char*)Vt[0] + sAd1) = vr1;
    int cur = 0;

    for (int kt = 0; kt <= ktend; ++kt) {
        __syncthreads();
        if (kt < ktend) {
            const u16* nK = gK + (size_t)(kt + 1) * 64 * 64;
            const u16* nV = gV + (size_t)(kt + 1) * 64;
            kr0 = *(const u16x8*)(nK);
            kr1 = *(const u16x8*)(nK + 32 * 64);
            vr0 = *(const u16x8*)(nV);
            vr1 = *(const u16x8*)(nV + 32 * 2048);
        }
        if (kt <= ktmax_w) {
            const char* Kc = (const char*)Kt[cur];
            const char* Vc = (const char*)Vt[cur];

            f32x4 sl[4] = {}, sh[4] = {};
#pragma unroll
            for (int j = 0; j < 4; ++j) {
                unsigned rb = (unsigned)((16 * j + c) * 128 + g * 16);
                bf16x8 ka0 = *(const bf16x8*)(Kc + (rb ^ swz));
                bf16x8 ka1 = *(const bf16x8*)(Kc + ((rb + 64) ^ swz));
                sl[j] = __builtin_amdgcn_mfma_f32_16x16x32_bf16(ka0, bq0l, sl[j], 0, 0, 0);
                sl[j] = __builtin_amdgcn_mfma_f32_16x16x32_bf16(ka1, bq1l, sl[j], 0, 0, 0);
                sh[j] = __builtin_amdgcn_mfma_f32_16x16x32_bf16(ka0, bq0h, sh[j], 0, 0, 0);
                sh[j] = __builtin_amdgcn_mfma_f32_16x16x32_bf16(ka1, bq1h, sh[j], 0, 0, 0);
            }

            const int kvb = kt * 64 + 4 * g;
            if (kt * 64 + 63 > q0w) {
#pragma unroll
                for (int j = 0; j < 4; ++j)
#pragma unroll
                    for (int r = 0; r < 4; ++r)
                        if (kvb + 16 * j + r > qlo) sl[j][r] = -INFINITY;
            }
            if (kt * 64 + 63 > q0w + 16) {
#pragma unroll
                for (int j = 0; j < 4; ++j)
#pragma unroll
                    for (int r = 0; r < 4; ++r)
                        if (kvb + 16 * j + r > qhi) sh[j][r] = -INFINITY;
            }

#pragma unroll
            for (int half = 0; half < 2; ++half) {
                f32x4* s = half ? sh : sl;
                float& m_r = half ? m_hi : m_lo;
                float& l_r = half ? l_hi : l_lo;
                f32x4* acc = half ? accH : accL;
                float mx = -INFINITY;
#pragma unroll
                for (int j = 0; j < 4; ++j)
#pragma unroll
                    for (int r = 0; r < 4; ++r) mx = fmaxf(mx, s[j][r]);
                mx = fmaxf(mx, __shfl_xor(mx, 16));
                mx = fmaxf(mx, __shfl_xor(mx, 32));
                if (!__all((mx - m_r) * CSC <= 8.f)) {
                    float mn = fmaxf(m_r, mx);
                    float al = exp2v((m_r - mn) * CSC);
                    l_r *= al;
#pragma unroll
                    for (int dj = 0; dj < 4; ++dj) acc[dj] *= al;
                    m_r = mn;
                }
                const float mc = m_r * CSC;
                float sum = 0.f;
                u32 pp[8];
#pragma unroll
                for (int j = 0; j < 4; ++j) {
#pragma unroll
                    for (int t2 = 0; t2 < 2; ++t2) {
                        float p0 = exp2v(fmaf(s[j][2 * t2], CSC, -mc));
                        float p1 = exp2v(fmaf(s[j][2 * t2 + 1], CSC, -mc));
                        sum += p0 + p1;
                        pp[j * 2 + t2] = cvtpk(p0, p1);
                    }
                }
                sum += __shfl_xor(sum, 16);
                sum += __shfl_xor(sum, 32);
                l_r += sum;
                unsigned rq = (unsigned)(c + 16 * half) * 128;
#pragma unroll
                for (int j = 0; j < 4; ++j) {
                    uint2 w2;
                    w2.x = pp[j * 2];
                    w2.y = pp[j * 2 + 1];
                    *(uint2*)(pw + ((rq + j * 32 + g * 8) ^ swz)) = w2;
                }
            }

#pragma unroll
            for (int ks = 0; ks < 2; ++ks) {
                bf16x8 pbl = *(const bf16x8*)(pw + ((unsigned)(c * 128 + ks * 64 + g * 16) ^ swz));
                bf16x8 pbh = *(const bf16x8*)(pw + ((unsigned)((c + 16) * 128 + ks * 64 + g * 16) ^ swz));
#pragma unroll
                for (int dj = 0; dj < 4; ++dj) {
                    unsigned vb = (unsigned)((dj * 16 + c) * 128 + ks * 64 + g * 16) ^ swz;
                    bf16x8 va = *(const bf16x8*)(Vc + vb);
                    accL[dj] = __builtin_amdgcn_mfma_f32_16x16x32_bf16(va, pbl, accL[dj], 0, 0, 0);
                    accH[dj] = __builtin_amdgcn_mfma_f32_16x16x32_bf16(va, pbh, accH[dj], 0, 0, 0);
                }
            }
        }

        if (kt < ktend) {
            int nb = cur ^ 1;
            *(u16x8*)((char*)Kt[nb] + sAd0) = kr0;
            *(u16x8*)((char*)Kt[nb] + sAd1) = kr1;
            *(u16x8*)((char*)Vt[nb] + sAd0) = vr0;
            *(u16x8*)((char*)Vt[nb] + sAd1) = vr1;
            cur = nb;
        }
    }

#pragma unroll
    for (int half = 0; half < 2; ++half) {
        const f32x4* acc = half ? accH : accL;
        float inv = 1.f / (half ? l_hi : l_lo);
        int q = half ? qhi : qlo;
        u16* ob = Ob + ((size_t)b * 2048 + q) * 1024 + h * 64;
#pragma unroll
        for (int dj = 0; dj < 4; ++dj) {
            f32x4 o = acc[dj] * inv;
            uint2 w;
            w.x = cvtpk(o[0], o[1]);
            w.y = cvtpk(o[2], o[3]);
            *(uint2*)(ob + dj * 16 + 4 * g) = w;
        }
    }
}

// ---------------------------------------------------------------------------
extern "C" void kernel_launch(void* const* d_in, const int* in_sizes, int n_in,
                              void* d_out, int out_size, void* d_ws, size_t ws_size,
                              hipStream_t stream) {
    const float* x = (const float*)d_in[0];
    const float* Wqkv = (const float*)d_in[1];
    const float* bqkv = (const float*)d_in[2];
    const float* Wproj = (const float*)d_in[3];
    const float* bproj = (const float*)d_in[4];
    float* out = (float*)d_out;

    char* ws = (char*)d_ws;
    u16* xb = (u16*)(ws);                       // 16,777,216 B; reused as Ob
    u16* WqkvT = (u16*)(ws + 16777216);         //  6,291,456 B
    u16* WprojT = (u16*)(ws + 23068672);        //  2,097,152 B
    u16* Qb = (u16*)(ws + 25165824);            // 16,777,216 B
    u16* Kb = (u16*)(ws + 41943040);            // 16,777,216 B
    u16* VbT = (u16*)(ws + 58720256);           // 16,777,216 B
    float2* tab = (float2*)(ws + 75497472);     //    524,288 B  (total ~76 MB)

    hipFuncSetAttribute((const void*)gemm_qkv,
                        hipFuncAttributeMaxDynamicSharedMemorySize, 81920);

    prep<<<5376, 256, 0, stream>>>(x, xb, Wqkv, WqkvT, Wproj, WprojT, tab);
    gemm_qkv<<<1024, 384, 81920, stream>>>(xb, WqkvT, bqkv, Qb, Kb, VbT);
    rope_ip<<<16384, 256, 0, stream>>>(Kb, tab);
    attn_fwd<<<1024, 256, 0, stream>>>(Qb, Kb, VbT, xb /*Ob*/, tab);
    gemm_proj<<<512, 256, 0, stream>>>(xb, WprojT, bproj, out, 1024, 8);
}

// Round 13
// 213.873 us; speedup vs baseline: 1.1647x; 1.1647x over previous
//
#include <hip/hip_runtime.h>
#include <math.h>

typedef unsigned short u16;
typedef unsigned int u32;
typedef __attribute__((ext_vector_type(8))) __bf16 bf16x8;
typedef __attribute__((ext_vector_type(4))) float f32x4;
typedef __attribute__((ext_vector_type(8))) unsigned short u16x8;

__device__ __forceinline__ u16 f2bf(float f) {
    u32 u = __builtin_bit_cast(u32, f);
    u32 r = (u + 0x7fffu + ((u >> 16) & 1u)) >> 16;
    return (u16)r;
}
__device__ __forceinline__ float bf2f(u16 h) {
    return __builtin_bit_cast(float, (u32)h << 16);
}
__device__ __forceinline__ float exp2v(float x) {
    float r;
    asm("v_exp_f32 %0, %1" : "=v"(r) : "v"(x));
    return r;
}
__device__ __forceinline__ u32 cvtpk(float lo, float hi) {
    u32 r;
    asm("v_cvt_pk_bf16_f32 %0, %1, %2" : "=v"(r) : "v"(lo), "v"(hi));
    return r;
}

#define GL16(gp, lp) __builtin_amdgcn_global_load_lds( \
    (const __attribute__((address_space(1))) u32*)(gp), \
    (__attribute__((address_space(3))) u32*)(lp), 16, 0, 0)

// RoPE a bf16x8 fragment: 4 (even,odd) pairs, cs4 = 4 (cos,sin) entries
__device__ __forceinline__ bf16x8 ropeQK(bf16x8 v, const float2* __restrict__ cs4) {
    union { bf16x8 b; u32 w[4]; } in, out;
    in.b = v;
#pragma unroll
    for (int i = 0; i < 4; ++i) {
        float2 cs = cs4[i];
        float e = bf2f((u16)(in.w[i] & 0xffff));
        float o = bf2f((u16)(in.w[i] >> 16));
        out.w[i] = cvtpk(e * cs.x - o * cs.y, fmaf(e, cs.y, o * cs.x));
    }
    return out.b;
}

// ---------------------------------------------------------------------------
// prep: merged f2bker (blocks 0..4095) + wtrans Wqkv (4096..4863) +
// wtrans Wproj (4864..5119) + rope_tab (5120..5375).
__global__ __launch_bounds__(256) void prep(
    const float* __restrict__ x, u16* __restrict__ xb,
    const float* __restrict__ Wqkv, u16* __restrict__ WqkvT,
    const float* __restrict__ Wproj, u16* __restrict__ WprojT,
    float2* __restrict__ tab) {
    __shared__ u16 t[64 * 65];
    const int bid = (int)blockIdx.x;
    const int tid = threadIdx.x;

    if (bid < 4096) {
        size_t i = ((size_t)bid * 256 + tid) * 8;
        float4 a = *(const float4*)(x + i);
        float4 b = *(const float4*)(x + i + 4);
        u16x8 w;
        w[0] = f2bf(a.x); w[1] = f2bf(a.y); w[2] = f2bf(a.z); w[3] = f2bf(a.w);
        w[4] = f2bf(b.x); w[5] = f2bf(b.y); w[6] = f2bf(b.z); w[7] = f2bf(b.w);
        *(u16x8*)(xb + i) = w;
        return;
    }
    if (bid < 5120) {
        const float* in; u16* out; int R = 1024, C; int c0, r0;
        if (bid < 4864) {
            in = Wqkv; out = WqkvT; C = 3072;
            int idx = bid - 4096;
            c0 = (idx % 48) * 64; r0 = (idx / 48) * 64;
        } else {
            in = Wproj; out = WprojT; C = 1024;
            int idx = bid - 4864;
            c0 = (idx % 16) * 64; r0 = (idx / 16) * 64;
        }
#pragma unroll
        for (int it = 0; it < 4; ++it) {
            int f = it * 256 + tid;
            int row = f >> 4, c4 = (f & 15) * 4;
            float4 v = *(const float4*)(in + (size_t)(r0 + row) * C + c0 + c4);
            t[row * 65 + c4 + 0] = f2bf(v.x);
            t[row * 65 + c4 + 1] = f2bf(v.y);
            t[row * 65 + c4 + 2] = f2bf(v.z);
            t[row * 65 + c4 + 3] = f2bf(v.w);
        }
        __syncthreads();
#pragma unroll
        for (int it = 0; it < 2; ++it) {
            int f = it * 256 + tid;
            int oc = f >> 3, r8 = (f & 7) * 8;
            u16x8 w;
#pragma unroll
            for (int j = 0; j < 8; ++j) w[j] = t[(r8 + j) * 65 + oc];
            *(u16x8*)(out + (size_t)(c0 + oc) * R + r0 + r8) = w;
        }
        return;
    }
    {
        int i = (bid - 5120) * 256 + tid;   // 65536
        int tpos = i >> 5, d2 = i & 31;
        float invf = powf(10000.f, -(float)(2 * d2) / 64.f);
        float fr = (float)tpos * invf;
        tab[i] = make_float2(cosf(fr), sinf(fr));
    }
}

// ---------------------------------------------------------------------------
// Depth-2 counted-vmcnt pipelined GEMM (r11 verified body): BK=64, 128x128,
// 256 threads = 4 waves (2x2, 64x64), double-buffered 64 KiB LDS -> 2
// blocks/CU, 2D-clustered-per-XCD mapping. MODE 0: fp32 out + bias.
// MODE 1: qkv scatter; K gets RoPE fused in-epilogue (lanes c,c^1 hold the
// (even,odd) pair of the same K row -> one shfl_xor + fma).
template <int MODE>
__global__ __launch_bounds__(256, 2) void gemm2p(
    const u16* __restrict__ A, const u16* __restrict__ Bt,
    const float* __restrict__ bias, float* __restrict__ Cf,
    u16* __restrict__ Qb, u16* __restrict__ Kb, u16* __restrict__ VbT,
    const float2* __restrict__ tab, int N, int nbx) {
    __shared__ __align__(16) u16 ls[2][2][128 * 64];   // [buf][A/B][row][col]
    const int tid = threadIdx.x;
    const int w = tid >> 6, lane = tid & 63;
    const int c = lane & 15, g = lane >> 4;
    const int wr = w >> 1, wc = w & 1;

    // 2D-clustered XCD mapping (bijective; nbx % 4 == 0)
    const int bid = (int)blockIdx.x;
    const int xcd = bid & 7, s = bid >> 3;
    const int ncc = nbx >> 2;
    const int cidx = s >> 4, w2 = s & 15;
    const int by = xcd * 8 + (cidx / ncc) * 4 + (w2 >> 2);
    const int bx = (cidx % ncc) * 4 + (w2 & 3);
    const int m0 = by * 128, n0 = bx * 128;

    f32x4 acc[4][4] = {};

    const int rl = tid >> 3;                   // 0..31
    const unsigned cb = ((unsigned)(tid & 7) * 16) ^ (((unsigned)rl & 7) << 4);
    const u16* gA = A + (size_t)(m0 + rl) * 1024 + (cb >> 1);
    const u16* gB = Bt + (size_t)(n0 + rl) * 1024 + (cb >> 1);
    const unsigned wb = (unsigned)__builtin_amdgcn_readfirstlane(w * 1024);
    char* lsb = (char*)ls;

#define STAGE(t_, buf_) do {                                                  \
        const u16* _ga = gA + (t_) * 64;                                      \
        const u16* _gb = gB + (t_) * 64;                                      \
        char* _la = lsb + (buf_) * 32768 + wb;                                \
        char* _lb = _la + 16384;                                              \
        GL16(_ga, _la);                                                       \
        GL16(_ga + 32 * 1024, _la + 4096);                                    \
        GL16(_ga + 64 * 1024, _la + 8192);                                    \
        GL16(_ga + 96 * 1024, _la + 12288);                                   \
        GL16(_gb, _lb);                                                       \
        GL16(_gb + 32 * 1024, _lb + 4096);                                    \
        GL16(_gb + 64 * 1024, _lb + 8192);                                    \
        GL16(_gb + 96 * 1024, _lb + 12288);                                   \
    } while (0)

    const unsigned swz = ((unsigned)(c & 7)) << 4;

    STAGE(0, 0);
    STAGE(1, 1);

    for (int t = 0; t < 16; ++t) {
        const int buf = t & 1;
        __builtin_amdgcn_sched_barrier(0);
        if (t == 15) asm volatile("s_waitcnt vmcnt(0)" ::: "memory");
        else         asm volatile("s_waitcnt vmcnt(8)" ::: "memory");
        __builtin_amdgcn_sched_barrier(0);
        __builtin_amdgcn_s_barrier();           // buf[t&1] fully staged
        __builtin_amdgcn_sched_barrier(0);

        const char* la = lsb + buf * 32768;
        const char* lb2 = la + 16384;
        bf16x8 af[4][2], bfr[4][2];
#pragma unroll
        for (int i = 0; i < 4; ++i) {
            unsigned rb = (unsigned)((wr * 64 + i * 16 + c) * 128);
            af[i][0] = *(const bf16x8*)(la + ((rb + g * 16) ^ swz));
            af[i][1] = *(const bf16x8*)(la + ((rb + 64 + g * 16) ^ swz));
        }
#pragma unroll
        for (int j = 0; j < 4; ++j) {
            unsigned rb = (unsigned)((wc * 64 + j * 16 + c) * 128);
            bfr[j][0] = *(const bf16x8*)(lb2 + ((rb + g * 16) ^ swz));
            bfr[j][1] = *(const bf16x8*)(lb2 + ((rb + 64 + g * 16) ^ swz));
        }
        __builtin_amdgcn_s_setprio(1);
#pragma unroll
        for (int i = 0; i < 4; ++i)
#pragma unroll
            for (int j = 0; j < 4; ++j) {
                acc[i][j] = __builtin_amdgcn_mfma_f32_16x16x32_bf16(af[i][0], bfr[j][0], acc[i][j], 0, 0, 0);
                acc[i][j] = __builtin_amdgcn_mfma_f32_16x16x32_bf16(af[i][1], bfr[j][1], acc[i][j], 0, 0, 0);
            }
        __builtin_amdgcn_s_setprio(0);
        __builtin_amdgcn_sched_barrier(0);
        asm volatile("s_waitcnt lgkmcnt(0)" ::: "memory");
        __builtin_amdgcn_s_barrier();           // all reads of buf done
        __builtin_amdgcn_sched_barrier(0);
        if (t < 14) STAGE(t + 2, buf);          // overwrite buf for t+2
    }
#undef STAGE

    if (MODE == 0) {
#pragma unroll
        for (int i = 0; i < 4; ++i)
#pragma unroll
            for (int r = 0; r < 4; ++r) {
                int m = m0 + wr * 64 + i * 16 + g * 4 + r;
#pragma unroll
                for (int j = 0; j < 4; ++j) {
                    int n = n0 + wc * 64 + j * 16 + c;
                    Cf[(size_t)m * N + n] = acc[i][j][r] + bias[n];
                }
            }
    } else {
        const int part = n0 >> 10;             // uniform per tile (128 | 1024)
#pragma unroll
        for (int i = 0; i < 4; ++i)
#pragma unroll
            for (int r = 0; r < 4; ++r) {
                int m = m0 + wr * 64 + i * 16 + g * 4 + r;
                int b = m >> 11, tt = m & 2047;
#pragma unroll
                for (int j = 0; j < 4; ++j) {
                    int n = n0 + wc * 64 + j * 16 + c;
                    int e = n & 1023, hh = e >> 6, d = e & 63;
                    float v = acc[i][j][r] + bias[n];
                    if (part == 1) {           // K: rope in-register
                        float vp = __shfl_xor(v, 1);
                        float2 cs = tab[tt * 32 + (d >> 1)];
                        v = (c & 1) ? fmaf(vp, cs.y, v * cs.x)
                                    : fmaf(v, cs.x, -vp * cs.y);
                    }
                    u16 bv = f2bf(v);
                    if (part == 0)
                        Qb[(((size_t)b * 16 + hh) * 2048 + tt) * 64 + d] = bv;
                    else if (part == 1)
                        Kb[(((size_t)b * 16 + hh) * 2048 + tt) * 64 + d] = bv;
                    else
                        VbT[(((size_t)b * 16 + hh) * 64 + d) * 2048 + tt] = bv;
                }
            }
    }
}

// ---------------------------------------------------------------------------
// Flash attention, swapped-operand form; Q roped in-register at start
// (K arrives pre-roped from the QKV epilogue). 1024 blocks, 256 threads
// (4 waves x 32 q each; block = 128 q rows).
__global__ __launch_bounds__(256, 3) void attn_fwd(
    const u16* __restrict__ Qb, const u16* __restrict__ Kb,
    const u16* __restrict__ VbT, u16* __restrict__ Ob,
    const float2* __restrict__ tab) {
    __shared__ __align__(16) u16 Kt[2][4096];   // [buf][kv=64][d=64] swizzled
    __shared__ __align__(16) u16 Vt[2][4096];   // [buf][d=64][kv=64] swizzled
    __shared__ __align__(16) u16 Pt[4][2048];   // per-wave [q=32][kv=64] swizzled
    const int tid = threadIdx.x, wv = tid >> 6, lane = tid & 63;
    const int g = lane >> 4, c = lane & 15;
    const int bid = blockIdx.x;                 // 0..1023
    const int xcd = bid & 7, slot = bid >> 3;
    const int bh = (xcd << 3) | (slot >> 4);
    const int blk = 15 - (slot & 15);
    const int b = bh >> 4, h = bh & 15;
    const int q0 = blk * 128;
    const int q0w = q0 + wv * 32;
    const int qlo = q0w + c, qhi = q0w + 16 + c;
    const float CSC = 0.18033688011112042f;     // 0.125 * log2(e)

    const u16* qp = Qb + ((size_t)bh * 2048 + qlo) * 64 + g * 8;
    const float2* tql = tab + qlo * 32 + g * 4;
    const float2* tqh = tab + qhi * 32 + g * 4;
    bf16x8 bq0l = ropeQK(*(const bf16x8*)(qp), tql);
    bf16x8 bq1l = ropeQK(*(const bf16x8*)(qp + 32), tql + 16);
    bf16x8 bq0h = ropeQK(*(const bf16x8*)(qp + 16 * 64), tqh);
    bf16x8 bq1h = ropeQK(*(const bf16x8*)(qp + 16 * 64 + 32), tqh + 16);

    float m_lo = -INFINITY, l_lo = 0.f;
    float m_hi = -INFINITY, l_hi = 0.f;
    f32x4 accL[4] = {}, accH[4] = {};

    const int stRow = tid >> 3;                 // 0..31
    const int stCol = (tid & 7) * 8;            // 0..56
    const u16* gK = Kb + (size_t)bh * 2048 * 64 + (size_t)stRow * 64 + stCol;
    const u16* gV = VbT + (size_t)bh * 64 * 2048 + (size_t)stRow * 2048 + stCol;
    const unsigned sw8 = (unsigned)(stRow & 7) << 4;
    const unsigned sAd0 = ((unsigned)(stRow * 128 + stCol * 2)) ^ sw8;
    const unsigned sAd1 = ((unsigned)((stRow + 32) * 128 + stCol * 2)) ^ sw8;
    const unsigned swz = (unsigned)(c & 7) << 4;
    char* pw = (char*)&Pt[wv][0];

    const int ktend = 2 * blk + 1;
    const int ktmax_w = (q0w + 31) >> 6;

    u16x8 kr0 = *(const u16x8*)(gK);
    u16x8 kr1 = *(const u16x8*)(gK + 32 * 64);
    u16x8 vr0 = *(const u16x8*)(gV);
    u16x8 vr1 = *(const u16x8*)(gV + 32 * 2048);
    *(u16x8*)((char*)Kt[0] + sAd0) = kr0;
    *(u16x8*)((char*)Kt[0] + sAd1) = kr1;
    *(u16x8*)((char*)Vt[0] + sAd0) = vr0;
    *(u16x8*)((char*)Vt[0] + sAd1) = vr1;
    int cur = 0;

    for (int kt = 0; kt <= ktend; ++kt) {
        __syncthreads();
        if (kt < ktend) {
            const u16* nK = gK + (size_t)(kt + 1) * 64 * 64;
            const u16* nV = gV + (size_t)(kt + 1) * 64;
            kr0 = *(const u16x8*)(nK);
            kr1 = *(const u16x8*)(nK + 32 * 64);
            vr0 = *(const u16x8*)(nV);
            vr1 = *(const u16x8*)(nV + 32 * 2048);
        }
        if (kt <= ktmax_w) {
            const char* Kc = (const char*)Kt[cur];
            const char* Vc = (const char*)Vt[cur];

            f32x4 sl[4] = {}, sh[4] = {};
#pragma unroll
            for (int j = 0; j < 4; ++j) {
                unsigned rb = (unsigned)((16 * j + c) * 128 + g * 16);
                bf16x8 ka0 = *(const bf16x8*)(Kc + (rb ^ swz));
                bf16x8 ka1 = *(const bf16x8*)(Kc + ((rb + 64) ^ swz));
                sl[j] = __builtin_amdgcn_mfma_f32_16x16x32_bf16(ka0, bq0l, sl[j], 0, 0, 0);
                sl[j] = __builtin_amdgcn_mfma_f32_16x16x32_bf16(ka1, bq1l, sl[j], 0, 0, 0);
                sh[j] = __builtin_amdgcn_mfma_f32_16x16x32_bf16(ka0, bq0h, sh[j], 0, 0, 0);
                sh[j] = __builtin_amdgcn_mfma_f32_16x16x32_bf16(ka1, bq1h, sh[j], 0, 0, 0);
            }

            const int kvb = kt * 64 + 4 * g;
            if (kt * 64 + 63 > q0w) {
#pragma unroll
                for (int j = 0; j < 4; ++j)
#pragma unroll
                    for (int r = 0; r < 4; ++r)
                        if (kvb + 16 * j + r > qlo) sl[j][r] = -INFINITY;
            }
            if (kt * 64 + 63 > q0w + 16) {
#pragma unroll
                for (int j = 0; j < 4; ++j)
#pragma unroll
                    for (int r = 0; r < 4; ++r)
                        if (kvb + 16 * j + r > qhi) sh[j][r] = -INFINITY;
            }

#pragma unroll
            for (int half = 0; half < 2; ++half) {
                f32x4* s = half ? sh : sl;
                float& m_r = half ? m_hi : m_lo;
                float& l_r = half ? l_hi : l_lo;
                f32x4* acc = half ? accH : accL;
                float mx = -INFINITY;
#pragma unroll
                for (int j = 0; j < 4; ++j)
#pragma unroll
                    for (int r = 0; r < 4; ++r) mx = fmaxf(mx, s[j][r]);
                mx = fmaxf(mx, __shfl_xor(mx, 16));
                mx = fmaxf(mx, __shfl_xor(mx, 32));
                if (!__all((mx - m_r) * CSC <= 8.f)) {
                    float mn = fmaxf(m_r, mx);
                    float al = exp2v((m_r - mn) * CSC);
                    l_r *= al;
#pragma unroll
                    for (int dj = 0; dj < 4; ++dj) acc[dj] *= al;
                    m_r = mn;
                }
                const float mc = m_r * CSC;
                float sum = 0.f;
                u32 pp[8];
#pragma unroll
                for (int j = 0; j < 4; ++j) {
#pragma unroll
                    for (int t2 = 0; t2 < 2; ++t2) {
                        float p0 = exp2v(fmaf(s[j][2 * t2], CSC, -mc));
                        float p1 = exp2v(fmaf(s[j][2 * t2 + 1], CSC, -mc));
                        sum += p0 + p1;
                        pp[j * 2 + t2] = cvtpk(p0, p1);
                    }
                }
                sum += __shfl_xor(sum, 16);
                sum += __shfl_xor(sum, 32);
                l_r += sum;
                unsigned rq = (unsigned)(c + 16 * half) * 128;
#pragma unroll
                for (int j = 0; j < 4; ++j) {
                    uint2 w2;
                    w2.x = pp[j * 2];
                    w2.y = pp[j * 2 + 1];
                    *(uint2*)(pw + ((rq + j * 32 + g * 8) ^ swz)) = w2;
                }
            }

#pragma unroll
            for (int ks = 0; ks < 2; ++ks) {
                bf16x8 pbl = *(const bf16x8*)(pw + ((unsigned)(c * 128 + ks * 64 + g * 16) ^ swz));
                bf16x8 pbh = *(const bf16x8*)(pw + ((unsigned)((c + 16) * 128 + ks * 64 + g * 16) ^ swz));
#pragma unroll
                for (int dj = 0; dj < 4; ++dj) {
                    unsigned vb = (unsigned)((dj * 16 + c) * 128 + ks * 64 + g * 16) ^ swz;
                    bf16x8 va = *(const bf16x8*)(Vc + vb);
                    accL[dj] = __builtin_amdgcn_mfma_f32_16x16x32_bf16(va, pbl, accL[dj], 0, 0, 0);
                    accH[dj] = __builtin_amdgcn_mfma_f32_16x16x32_bf16(va, pbh, accH[dj], 0, 0, 0);
                }
            }
        }

        if (kt < ktend) {
            int nb = cur ^ 1;
            *(u16x8*)((char*)Kt[nb] + sAd0) = kr0;
            *(u16x8*)((char*)Kt[nb] + sAd1) = kr1;
            *(u16x8*)((char*)Vt[nb] + sAd0) = vr0;
            *(u16x8*)((char*)Vt[nb] + sAd1) = vr1;
            cur = nb;
        }
    }

#pragma unroll
    for (int half = 0; half < 2; ++half) {
        const f32x4* acc = half ? accH : accL;
        float inv = 1.f / (half ? l_hi : l_lo);
        int q = half ? qhi : qlo;
        u16* ob = Ob + ((size_t)b * 2048 + q) * 1024 + h * 64;
#pragma unroll
        for (int dj = 0; dj < 4; ++dj) {
            f32x4 o = acc[dj] * inv;
            uint2 w;
            w.x = cvtpk(o[0], o[1]);
            w.y = cvtpk(o[2], o[3]);
            *(uint2*)(ob + dj * 16 + 4 * g) = w;
        }
    }
}

// ---------------------------------------------------------------------------
extern "C" void kernel_launch(void* const* d_in, const int* in_sizes, int n_in,
                              void* d_out, int out_size, void* d_ws, size_t ws_size,
                              hipStream_t stream) {
    const float* x = (const float*)d_in[0];
    const float* Wqkv = (const float*)d_in[1];
    const float* bqkv = (const float*)d_in[2];
    const float* Wproj = (const float*)d_in[3];
    const float* bproj = (const float*)d_in[4];
    float* out = (float*)d_out;

    char* ws = (char*)d_ws;
    u16* xb = (u16*)(ws);                       // 16,777,216 B; reused as Ob
    u16* WqkvT = (u16*)(ws + 16777216);         //  6,291,456 B
    u16* WprojT = (u16*)(ws + 23068672);        //  2,097,152 B
    u16* Qb = (u16*)(ws + 25165824);            // 16,777,216 B
    u16* Kb = (u16*)(ws + 41943040);            // 16,777,216 B
    u16* VbT = (u16*)(ws + 58720256);           // 16,777,216 B
    float2* tab = (float2*)(ws + 75497472);     //    524,288 B  (total ~76 MB)

    prep<<<5376, 256, 0, stream>>>(x, xb, Wqkv, WqkvT, Wproj, WprojT, tab);
    gemm2p<1><<<1536, 256, 0, stream>>>(xb, WqkvT, bqkv, nullptr, Qb, Kb, VbT,
                                        tab, 3072, 24);
    attn_fwd<<<1024, 256, 0, stream>>>(Qb, Kb, VbT, xb /*Ob*/, tab);
    gemm2p<0><<<512, 256, 0, stream>>>(xb, WprojT, bproj, out,
                                       nullptr, nullptr, nullptr, tab, 1024, 8);
}

// Round 14
// 200.384 us; speedup vs baseline: 1.2431x; 1.0673x over previous
//
#include <hip/hip_runtime.h>
#include <math.h>

typedef unsigned short u16;
typedef unsigned int u32;
typedef __attribute__((ext_vector_type(8))) __bf16 bf16x8;
typedef __attribute__((ext_vector_type(4))) float f32x4;
typedef __attribute__((ext_vector_type(8))) unsigned short u16x8;

__device__ __forceinline__ u16 f2bf(float f) {
    u32 u = __builtin_bit_cast(u32, f);
    u32 r = (u + 0x7fffu + ((u >> 16) & 1u)) >> 16;
    return (u16)r;
}
__device__ __forceinline__ float bf2f(u16 h) {
    return __builtin_bit_cast(float, (u32)h << 16);
}
__device__ __forceinline__ float exp2v(float x) {
    float r;
    asm("v_exp_f32 %0, %1" : "=v"(r) : "v"(x));
    return r;
}
__device__ __forceinline__ u32 cvtpk(float lo, float hi) {
    u32 r;
    asm("v_cvt_pk_bf16_f32 %0, %1, %2" : "=v"(r) : "v"(lo), "v"(hi));
    return r;
}

#define GL16(gp, lp) __builtin_amdgcn_global_load_lds( \
    (const __attribute__((address_space(1))) u32*)(gp), \
    (__attribute__((address_space(3))) u32*)(lp), 16, 0, 0)

// RoPE a bf16x8 fragment: 4 (even,odd) pairs, cs4 = 4 (cos,sin) entries
__device__ __forceinline__ bf16x8 ropeQK(bf16x8 v, const float2* __restrict__ cs4) {
    union { bf16x8 b; u32 w[4]; } in, out;
    in.b = v;
#pragma unroll
    for (int i = 0; i < 4; ++i) {
        float2 cs = cs4[i];
        float e = bf2f((u16)(in.w[i] & 0xffff));
        float o = bf2f((u16)(in.w[i] >> 16));
        out.w[i] = cvtpk(e * cs.x - o * cs.y, fmaf(e, cs.y, o * cs.x));
    }
    return out.b;
}

// ---------------------------------------------------------------------------
// prep: merged f2bker (blocks 0..4095) + wtrans Wqkv (4096..4863) +
// wtrans Wproj (4864..5119) + rope_tab (5120..5375).
__global__ __launch_bounds__(256) void prep(
    const float* __restrict__ x, u16* __restrict__ xb,
    const float* __restrict__ Wqkv, u16* __restrict__ WqkvT,
    const float* __restrict__ Wproj, u16* __restrict__ WprojT,
    float2* __restrict__ tab) {
    __shared__ u16 t[64 * 65];
    const int bid = (int)blockIdx.x;
    const int tid = threadIdx.x;

    if (bid < 4096) {
        size_t i = ((size_t)bid * 256 + tid) * 8;
        float4 a = *(const float4*)(x + i);
        float4 b = *(const float4*)(x + i + 4);
        u16x8 w;
        w[0] = f2bf(a.x); w[1] = f2bf(a.y); w[2] = f2bf(a.z); w[3] = f2bf(a.w);
        w[4] = f2bf(b.x); w[5] = f2bf(b.y); w[6] = f2bf(b.z); w[7] = f2bf(b.w);
        *(u16x8*)(xb + i) = w;
        return;
    }
    if (bid < 5120) {
        const float* in; u16* out; int R = 1024, C; int c0, r0;
        if (bid < 4864) {
            in = Wqkv; out = WqkvT; C = 3072;
            int idx = bid - 4096;
            c0 = (idx % 48) * 64; r0 = (idx / 48) * 64;
        } else {
            in = Wproj; out = WprojT; C = 1024;
            int idx = bid - 4864;
            c0 = (idx % 16) * 64; r0 = (idx / 16) * 64;
        }
#pragma unroll
        for (int it = 0; it < 4; ++it) {
            int f = it * 256 + tid;
            int row = f >> 4, c4 = (f & 15) * 4;
            float4 v = *(const float4*)(in + (size_t)(r0 + row) * C + c0 + c4);
            t[row * 65 + c4 + 0] = f2bf(v.x);
            t[row * 65 + c4 + 1] = f2bf(v.y);
            t[row * 65 + c4 + 2] = f2bf(v.z);
            t[row * 65 + c4 + 3] = f2bf(v.w);
        }
        __syncthreads();
#pragma unroll
        for (int it = 0; it < 2; ++it) {
            int f = it * 256 + tid;
            int oc = f >> 3, r8 = (f & 7) * 8;
            u16x8 w;
#pragma unroll
            for (int j = 0; j < 8; ++j) w[j] = t[(r8 + j) * 65 + oc];
            *(u16x8*)(out + (size_t)(c0 + oc) * R + r0 + r8) = w;
        }
        return;
    }
    {
        int i = (bid - 5120) * 256 + tid;   // 65536
        int tpos = i >> 5, d2 = i & 31;
        float invf = powf(10000.f, -(float)(2 * d2) / 64.f);
        float fr = (float)tpos * invf;
        tab[i] = make_float2(cosf(fr), sinf(fr));
    }
}

// RoPE in-place on K only (B,H,T,D) bf16 (Q is roped inside attn)
__global__ __launch_bounds__(256) void rope_ip(u16* __restrict__ K,
                                               const float2* __restrict__ tab) {
    int i = blockIdx.x * 256 + threadIdx.x;   // 4,194,304 pairs
    u32* p = (u32*)K + i;
    int d2 = i & 31, tpos = (i >> 5) & 2047;
    float2 cs = tab[tpos * 32 + d2];
    u32 v = *p;
    float xe = bf2f((u16)(v & 0xffff));
    float xo = bf2f((u16)(v >> 16));
    float re = xe * cs.x - xo * cs.y;
    float ro = xe * cs.y + xo * cs.x;
    *p = (u32)f2bf(re) | ((u32)f2bf(ro) << 16);
}

// ---------------------------------------------------------------------------
// Depth-2 counted-vmcnt pipelined GEMM (r11 verified body, 104 us QKV):
// BK=64, 128x128, 256 threads = 4 waves (2x2, 64x64), double-buffered
// 64 KiB LDS -> 2 blocks/CU, 2D-clustered-per-XCD mapping.
// MODE 0: fp32 out + bias. MODE 1: qkv scatter (V transposed), NO rope.
template <int MODE>
__global__ __launch_bounds__(256, 2) void gemm2p(
    const u16* __restrict__ A, const u16* __restrict__ Bt,
    const float* __restrict__ bias, float* __restrict__ Cf,
    u16* __restrict__ Qb, u16* __restrict__ Kb, u16* __restrict__ VbT,
    int N, int nbx) {
    __shared__ __align__(16) u16 ls[2][2][128 * 64];   // [buf][A/B][row][col]
    const int tid = threadIdx.x;
    const int w = tid >> 6, lane = tid & 63;
    const int c = lane & 15, g = lane >> 4;
    const int wr = w >> 1, wc = w & 1;

    // 2D-clustered XCD mapping (bijective; nbx % 4 == 0)
    const int bid = (int)blockIdx.x;
    const int xcd = bid & 7, s = bid >> 3;
    const int ncc = nbx >> 2;
    const int cidx = s >> 4, w2 = s & 15;
    const int by = xcd * 8 + (cidx / ncc) * 4 + (w2 >> 2);
    const int bx = (cidx % ncc) * 4 + (w2 & 3);
    const int m0 = by * 128, n0 = bx * 128;

    f32x4 acc[4][4] = {};

    const int rl = tid >> 3;                   // 0..31
    const unsigned cb = ((unsigned)(tid & 7) * 16) ^ (((unsigned)rl & 7) << 4);
    const u16* gA = A + (size_t)(m0 + rl) * 1024 + (cb >> 1);
    const u16* gB = Bt + (size_t)(n0 + rl) * 1024 + (cb >> 1);
    const unsigned wb = (unsigned)__builtin_amdgcn_readfirstlane(w * 1024);
    char* lsb = (char*)ls;

#define STAGE(t_, buf_) do {                                                  \
        const u16* _ga = gA + (t_) * 64;                                      \
        const u16* _gb = gB + (t_) * 64;                                      \
        char* _la = lsb + (buf_) * 32768 + wb;                                \
        char* _lb = _la + 16384;                                              \
        GL16(_ga, _la);                                                       \
        GL16(_ga + 32 * 1024, _la + 4096);                                    \
        GL16(_ga + 64 * 1024, _la + 8192);                                    \
        GL16(_ga + 96 * 1024, _la + 12288);                                   \
        GL16(_gb, _lb);                                                       \
        GL16(_gb + 32 * 1024, _lb + 4096);                                    \
        GL16(_gb + 64 * 1024, _lb + 8192);                                    \
        GL16(_gb + 96 * 1024, _lb + 12288);                                   \
    } while (0)

    const unsigned swz = ((unsigned)(c & 7)) << 4;

    STAGE(0, 0);
    STAGE(1, 1);

    for (int t = 0; t < 16; ++t) {
        const int buf = t & 1;
        __builtin_amdgcn_sched_barrier(0);
        if (t == 15) asm volatile("s_waitcnt vmcnt(0)" ::: "memory");
        else         asm volatile("s_waitcnt vmcnt(8)" ::: "memory");
        __builtin_amdgcn_sched_barrier(0);
        __builtin_amdgcn_s_barrier();           // buf[t&1] fully staged
        __builtin_amdgcn_sched_barrier(0);

        const char* la = lsb + buf * 32768;
        const char* lb2 = la + 16384;
        bf16x8 af[4][2], bfr[4][2];
#pragma unroll
        for (int i = 0; i < 4; ++i) {
            unsigned rb = (unsigned)((wr * 64 + i * 16 + c) * 128);
            af[i][0] = *(const bf16x8*)(la + ((rb + g * 16) ^ swz));
            af[i][1] = *(const bf16x8*)(la + ((rb + 64 + g * 16) ^ swz));
        }
#pragma unroll
        for (int j = 0; j < 4; ++j) {
            unsigned rb = (unsigned)((wc * 64 + j * 16 + c) * 128);
            bfr[j][0] = *(const bf16x8*)(lb2 + ((rb + g * 16) ^ swz));
            bfr[j][1] = *(const bf16x8*)(lb2 + ((rb + 64 + g * 16) ^ swz));
        }
        __builtin_amdgcn_s_setprio(1);
#pragma unroll
        for (int i = 0; i < 4; ++i)
#pragma unroll
            for (int j = 0; j < 4; ++j) {
                acc[i][j] = __builtin_amdgcn_mfma_f32_16x16x32_bf16(af[i][0], bfr[j][0], acc[i][j], 0, 0, 0);
                acc[i][j] = __builtin_amdgcn_mfma_f32_16x16x32_bf16(af[i][1], bfr[j][1], acc[i][j], 0, 0, 0);
            }
        __builtin_amdgcn_s_setprio(0);
        __builtin_amdgcn_sched_barrier(0);
        asm volatile("s_waitcnt lgkmcnt(0)" ::: "memory");
        __builtin_amdgcn_s_barrier();           // all reads of buf done
        __builtin_amdgcn_sched_barrier(0);
        if (t < 14) STAGE(t + 2, buf);          // overwrite buf for t+2
    }
#undef STAGE

    if (MODE == 0) {
#pragma unroll
        for (int i = 0; i < 4; ++i)
#pragma unroll
            for (int r = 0; r < 4; ++r) {
                int m = m0 + wr * 64 + i * 16 + g * 4 + r;
#pragma unroll
                for (int j = 0; j < 4; ++j) {
                    int n = n0 + wc * 64 + j * 16 + c;
                    Cf[(size_t)m * N + n] = acc[i][j][r] + bias[n];
                }
            }
    } else {
        const int part = n0 >> 10;             // uniform per tile
#pragma unroll
        for (int i = 0; i < 4; ++i)
#pragma unroll
            for (int r = 0; r < 4; ++r) {
                int m = m0 + wr * 64 + i * 16 + g * 4 + r;
                int b = m >> 11, tt = m & 2047;
#pragma unroll
                for (int j = 0; j < 4; ++j) {
                    int n = n0 + wc * 64 + j * 16 + c;
                    int e = n & 1023, hh = e >> 6, d = e & 63;
                    float v = acc[i][j][r] + bias[n];
                    u16 bv = f2bf(v);
                    if (part == 0)
                        Qb[(((size_t)b * 16 + hh) * 2048 + tt) * 64 + d] = bv;
                    else if (part == 1)
                        Kb[(((size_t)b * 16 + hh) * 2048 + tt) * 64 + d] = bv;
                    else
                        VbT[(((size_t)b * 16 + hh) * 64 + d) * 2048 + tt] = bv;
                }
            }
    }
}

// ---------------------------------------------------------------------------
// Flash attention, swapped-operand form; Q roped in-register at start
// (K arrives pre-roped from rope_ip). 1024 blocks, 256 threads
// (4 waves x 32 q each; block = 128 q rows).
__global__ __launch_bounds__(256, 3) void attn_fwd(
    const u16* __restrict__ Qb, const u16* __restrict__ Kb,
    const u16* __restrict__ VbT, u16* __restrict__ Ob,
    const float2* __restrict__ tab) {
    __shared__ __align__(16) u16 Kt[2][4096];   // [buf][kv=64][d=64] swizzled
    __shared__ __align__(16) u16 Vt[2][4096];   // [buf][d=64][kv=64] swizzled
    __shared__ __align__(16) u16 Pt[4][2048];   // per-wave [q=32][kv=64] swizzled
    const int tid = threadIdx.x, wv = tid >> 6, lane = tid & 63;
    const int g = lane >> 4, c = lane & 15;
    const int bid = blockIdx.x;                 // 0..1023
    const int xcd = bid & 7, slot = bid >> 3;
    const int bh = (xcd << 3) | (slot >> 4);
    const int blk = 15 - (slot & 15);
    const int b = bh >> 4, h = bh & 15;
    const int q0 = blk * 128;
    const int q0w = q0 + wv * 32;
    const int qlo = q0w + c, qhi = q0w + 16 + c;
    const float CSC = 0.18033688011112042f;     // 0.125 * log2(e)

    const u16* qp = Qb + ((size_t)bh * 2048 + qlo) * 64 + g * 8;
    const float2* tql = tab + qlo * 32 + g * 4;
    const float2* tqh = tab + qhi * 32 + g * 4;
    bf16x8 bq0l = ropeQK(*(const bf16x8*)(qp), tql);
    bf16x8 bq1l = ropeQK(*(const bf16x8*)(qp + 32), tql + 16);
    bf16x8 bq0h = ropeQK(*(const bf16x8*)(qp + 16 * 64), tqh);
    bf16x8 bq1h = ropeQK(*(const bf16x8*)(qp + 16 * 64 + 32), tqh + 16);

    float m_lo = -INFINITY, l_lo = 0.f;
    float m_hi = -INFINITY, l_hi = 0.f;
    f32x4 accL[4] = {}, accH[4] = {};

    const int stRow = tid >> 3;                 // 0..31
    const int stCol = (tid & 7) * 8;            // 0..56
    const u16* gK = Kb + (size_t)bh * 2048 * 64 + (size_t)stRow * 64 + stCol;
    const u16* gV = VbT + (size_t)bh * 64 * 2048 + (size_t)stRow * 2048 + stCol;
    const unsigned sw8 = (unsigned)(stRow & 7) << 4;
    const unsigned sAd0 = ((unsigned)(stRow * 128 + stCol * 2)) ^ sw8;
    const unsigned sAd1 = ((unsigned)((stRow + 32) * 128 + stCol * 2)) ^ sw8;
    const unsigned swz = (unsigned)(c & 7) << 4;
    char* pw = (char*)&Pt[wv][0];

    const int ktend = 2 * blk + 1;
    const int ktmax_w = (q0w + 31) >> 6;

    u16x8 kr0 = *(const u16x8*)(gK);
    u16x8 kr1 = *(const u16x8*)(gK + 32 * 64);
    u16x8 vr0 = *(const u16x8*)(gV);
    u16x8 vr1 = *(const u16x8*)(gV + 32 * 2048);
    *(u16x8*)((char*)Kt[0] + sAd0) = kr0;
    *(u16x8*)((char*)Kt[0] + sAd1) = kr1;
    *(u16x8*)((char*)Vt[0] + sAd0) = vr0;
    *(u16x8*)((char*)Vt[0] + sAd1) = vr1;
    int cur = 0;

    for (int kt = 0; kt <= ktend; ++kt) {
        __syncthreads();
        if (kt < ktend) {
            const u16* nK = gK + (size_t)(kt + 1) * 64 * 64;
            const u16* nV = gV + (size_t)(kt + 1) * 64;
            kr0 = *(const u16x8*)(nK);
            kr1 = *(const u16x8*)(nK + 32 * 64);
            vr0 = *(const u16x8*)(nV);
            vr1 = *(const u16x8*)(nV + 32 * 2048);
        }
        if (kt <= ktmax_w) {
            const char* Kc = (const char*)Kt[cur];
            const char* Vc = (const char*)Vt[cur];

            f32x4 sl[4] = {}, sh[4] = {};
#pragma unroll
            for (int j = 0; j < 4; ++j) {
                unsigned rb = (unsigned)((16 * j + c) * 128 + g * 16);
                bf16x8 ka0 = *(const bf16x8*)(Kc + (rb ^ swz));
                bf16x8 ka1 = *(const bf16x8*)(Kc + ((rb + 64) ^ swz));
                sl[j] = __builtin_amdgcn_mfma_f32_16x16x32_bf16(ka0, bq0l, sl[j], 0, 0, 0);
                sl[j] = __builtin_amdgcn_mfma_f32_16x16x32_bf16(ka1, bq1l, sl[j], 0, 0, 0);
                sh[j] = __builtin_amdgcn_mfma_f32_16x16x32_bf16(ka0, bq0h, sh[j], 0, 0, 0);
                sh[j] = __builtin_amdgcn_mfma_f32_16x16x32_bf16(ka1, bq1h, sh[j], 0, 0, 0);
            }

            const int kvb = kt * 64 + 4 * g;
            if (kt * 64 + 63 > q0w) {
#pragma unroll
                for (int j = 0; j < 4; ++j)
#pragma unroll
                    for (int r = 0; r < 4; ++r)
                        if (kvb + 16 * j + r > qlo) sl[j][r] = -INFINITY;
            }
            if (kt * 64 + 63 > q0w + 16) {
#pragma unroll
                for (int j = 0; j < 4; ++j)
#pragma unroll
                    for (int r = 0; r < 4; ++r)
                        if (kvb + 16 * j + r > qhi) sh[j][r] = -INFINITY;
            }

#pragma unroll
            for (int half = 0; half < 2; ++half) {
                f32x4* s = half ? sh : sl;
                float& m_r = half ? m_hi : m_lo;
                float& l_r = half ? l_hi : l_lo;
                f32x4* acc = half ? accH : accL;
                float mx = -INFINITY;
#pragma unroll
                for (int j = 0; j < 4; ++j)
#pragma unroll
                    for (int r = 0; r < 4; ++r) mx = fmaxf(mx, s[j][r]);
                mx = fmaxf(mx, __shfl_xor(mx, 16));
                mx = fmaxf(mx, __shfl_xor(mx, 32));
                if (!__all((mx - m_r) * CSC <= 8.f)) {
                    float mn = fmaxf(m_r, mx);
                    float al = exp2v((m_r - mn) * CSC);
                    l_r *= al;
#pragma unroll
                    for (int dj = 0; dj < 4; ++dj) acc[dj] *= al;
                    m_r = mn;
                }
                const float mc = m_r * CSC;
                float sum = 0.f;
                u32 pp[8];
#pragma unroll
                for (int j = 0; j < 4; ++j) {
#pragma unroll
                    for (int t2 = 0; t2 < 2; ++t2) {
                        float p0 = exp2v(fmaf(s[j][2 * t2], CSC, -mc));
                        float p1 = exp2v(fmaf(s[j][2 * t2 + 1], CSC, -mc));
                        sum += p0 + p1;
                        pp[j * 2 + t2] = cvtpk(p0, p1);
                    }
                }
                sum += __shfl_xor(sum, 16);
                sum += __shfl_xor(sum, 32);
                l_r += sum;
                unsigned rq = (unsigned)(c + 16 * half) * 128;
#pragma unroll
                for (int j = 0; j < 4; ++j) {
                    uint2 w2;
                    w2.x = pp[j * 2];
                    w2.y = pp[j * 2 + 1];
                    *(uint2*)(pw + ((rq + j * 32 + g * 8) ^ swz)) = w2;
                }
            }

#pragma unroll
            for (int ks = 0; ks < 2; ++ks) {
                bf16x8 pbl = *(const bf16x8*)(pw + ((unsigned)(c * 128 + ks * 64 + g * 16) ^ swz));
                bf16x8 pbh = *(const bf16x8*)(pw + ((unsigned)((c + 16) * 128 + ks * 64 + g * 16) ^ swz));
#pragma unroll
                for (int dj = 0; dj < 4; ++dj) {
                    unsigned vb = (unsigned)((dj * 16 + c) * 128 + ks * 64 + g * 16) ^ swz;
                    bf16x8 va = *(const bf16x8*)(Vc + vb);
                    accL[dj] = __builtin_amdgcn_mfma_f32_16x16x32_bf16(va, pbl, accL[dj], 0, 0, 0);
                    accH[dj] = __builtin_amdgcn_mfma_f32_16x16x32_bf16(va, pbh, accH[dj], 0, 0, 0);
                }
            }
        }

        if (kt < ktend) {
            int nb = cur ^ 1;
            *(u16x8*)((char*)Kt[nb] + sAd0) = kr0;
            *(u16x8*)((char*)Kt[nb] + sAd1) = kr1;
            *(u16x8*)((char*)Vt[nb] + sAd0) = vr0;
            *(u16x8*)((char*)Vt[nb] + sAd1) = vr1;
            cur = nb;
        }
    }

#pragma unroll
    for (int half = 0; half < 2; ++half) {
        const f32x4* acc = half ? accH : accL;
        float inv = 1.f / (half ? l_hi : l_lo);
        int q = half ? qhi : qlo;
        u16* ob = Ob + ((size_t)b * 2048 + q) * 1024 + h * 64;
#pragma unroll
        for (int dj = 0; dj < 4; ++dj) {
            f32x4 o = acc[dj] * inv;
            uint2 w;
            w.x = cvtpk(o[0], o[1]);
            w.y = cvtpk(o[2], o[3]);
            *(uint2*)(ob + dj * 16 + 4 * g) = w;
        }
    }
}

// ---------------------------------------------------------------------------
extern "C" void kernel_launch(void* const* d_in, const int* in_sizes, int n_in,
                              void* d_out, int out_size, void* d_ws, size_t ws_size,
                              hipStream_t stream) {
    const float* x = (const float*)d_in[0];
    const float* Wqkv = (const float*)d_in[1];
    const float* bqkv = (const float*)d_in[2];
    const float* Wproj = (const float*)d_in[3];
    const float* bproj = (const float*)d_in[4];
    float* out = (float*)d_out;

    char* ws = (char*)d_ws;
    u16* xb = (u16*)(ws);                       // 16,777,216 B; reused as Ob
    u16* WqkvT = (u16*)(ws + 16777216);         //  6,291,456 B
    u16* WprojT = (u16*)(ws + 23068672);        //  2,097,152 B
    u16* Qb = (u16*)(ws + 25165824);            // 16,777,216 B
    u16* Kb = (u16*)(ws + 41943040);            // 16,777,216 B
    u16* VbT = (u16*)(ws + 58720256);           // 16,777,216 B
    float2* tab = (float2*)(ws + 75497472);     //    524,288 B  (total ~76 MB)

    prep<<<5376, 256, 0, stream>>>(x, xb, Wqkv, WqkvT, Wproj, WprojT, tab);
    gemm2p<1><<<1536, 256, 0, stream>>>(xb, WqkvT, bqkv, nullptr, Qb, Kb, VbT,
                                        3072, 24);
    rope_ip<<<16384, 256, 0, stream>>>(Kb, tab);
    attn_fwd<<<1024, 256, 0, stream>>>(Qb, Kb, VbT, xb /*Ob*/, tab);
    gemm2p<0><<<512, 256, 0, stream>>>(xb, WprojT, bproj, out,
                                       nullptr, nullptr, nullptr, 1024, 8);
}